// Round 1
// baseline (213.657 us; speedup 1.0000x reference)
//
#include <hip/hip_runtime.h>
#include <float.h>

typedef __bf16 bf16;
typedef __bf16 bf16x8 __attribute__((ext_vector_type(8)));
typedef float f32x4 __attribute__((ext_vector_type(4)));

#define GAS __attribute__((address_space(1)))
#define LAS __attribute__((address_space(3)))

__device__ __forceinline__ void gload_lds16(const void* g, void* l) {
  __builtin_amdgcn_global_load_lds((const GAS unsigned int*)g, (LAS unsigned int*)l, 16, 0, 0);
}

// ---------------------------------------------------------------------------
// GEMM: C[M,N] = A[M,K] @ Bt[N,K]^T, A/Bt bf16 row-major, 128x128 tile, BK=32.
// 4 waves (2x2), each wave 64x64 = 4x4 fragments of 16x16x32 MFMA.
// LDS 16B slots XOR-swizzled by (row&3); global source pre-swizzled for
// global_load_lds (linear dest = wave base + lane*16).
// ---------------------------------------------------------------------------
template <int OUT_BF16>
__global__ __launch_bounds__(256, 2) void gemm_bt(
    const bf16* __restrict__ A, const bf16* __restrict__ Bt,
    void* __restrict__ Cv, int M, int N, int K) {
  __shared__ bf16 As[128 * 32];
  __shared__ bf16 Bs[128 * 32];
  const int tid = threadIdx.x;
  const int lane = tid & 63, w = tid >> 6;
  const int wr = w >> 1, wc = w & 1;
  const size_t m0 = (size_t)blockIdx.y * 128, n0 = (size_t)blockIdx.x * 128;
  const int srow = lane >> 2, sslot = lane & 3;
  const int g = lane >> 4, fr = lane & 15;

  f32x4 acc[4][4] = {};

  for (int kt = 0; kt < K; kt += 32) {
    __syncthreads();  // previous-iter frag reads done before overwrite
#pragma unroll
    for (int j = 0; j < 2; ++j) {
      const int c = 2 * w + j;        // 1KB chunk id (16 rows of 64B)
      const int r = c * 16 + srow;    // tile row 0..127
      const int ks = (sslot ^ (r & 3)) << 3;  // pre-swizzled global k-slot
      gload_lds16(A + (m0 + r) * K + kt + ks, &As[c * 512]);
      gload_lds16(Bt + (n0 + r) * K + kt + ks, &Bs[c * 512]);
    }
    __syncthreads();  // compiler drains vmcnt(0) here
    bf16x8 av[4], bv[4];
#pragma unroll
    for (int mi = 0; mi < 4; ++mi) {
      const int r = wr * 64 + mi * 16 + fr;
      av[mi] = *(const bf16x8*)&As[r * 32 + ((g ^ (r & 3)) << 3)];
    }
#pragma unroll
    for (int ni = 0; ni < 4; ++ni) {
      const int r = wc * 64 + ni * 16 + fr;
      bv[ni] = *(const bf16x8*)&Bs[r * 32 + ((g ^ (r & 3)) << 3)];
    }
#pragma unroll
    for (int mi = 0; mi < 4; ++mi)
#pragma unroll
      for (int ni = 0; ni < 4; ++ni)
        acc[mi][ni] = __builtin_amdgcn_mfma_f32_16x16x32_bf16(
            av[mi], bv[ni], acc[mi][ni], 0, 0, 0);
  }

#pragma unroll
  for (int mi = 0; mi < 4; ++mi)
#pragma unroll
    for (int ni = 0; ni < 4; ++ni)
#pragma unroll
      for (int rg = 0; rg < 4; ++rg) {
        const size_t row = m0 + wr * 64 + mi * 16 + g * 4 + rg;
        const size_t col = n0 + wc * 64 + ni * 16 + fr;
        if (OUT_BF16)
          ((bf16*)Cv)[row * (size_t)N + col] = (bf16)acc[mi][ni][rg];
        else
          ((float*)Cv)[row * (size_t)N + col] = acc[mi][ni][rg];
      }
}

// ---------------------------------------------------------------------------
// LayerNorm (biased var) + cast to bf16. One block per row of 2048.
// ---------------------------------------------------------------------------
__global__ __launch_bounds__(256) void ln_to_bf16(
    const float* __restrict__ x, const float* __restrict__ gamma,
    const float* __restrict__ beta, bf16* __restrict__ xn) {
  const int row = blockIdx.x, tid = threadIdx.x;
  const size_t base = (size_t)row * 2048 + tid * 8;
  f32x4 v0 = *(const f32x4*)(x + base);
  f32x4 v1 = *(const f32x4*)(x + base + 4);
  float s = 0.f, q2 = 0.f;
#pragma unroll
  for (int j = 0; j < 4; ++j) {
    s += v0[j] + v1[j];
    q2 += v0[j] * v0[j] + v1[j] * v1[j];
  }
  for (int off = 32; off > 0; off >>= 1) {
    s += __shfl_down(s, off);
    q2 += __shfl_down(q2, off);
  }
  __shared__ float red[8];
  const int lane = tid & 63, wv = tid >> 6;
  if (lane == 0) { red[wv] = s; red[4 + wv] = q2; }
  __syncthreads();
  s = red[0] + red[1] + red[2] + red[3];
  q2 = red[4] + red[5] + red[6] + red[7];
  const float mu = s * (1.f / 2048.f);
  const float var = q2 * (1.f / 2048.f) - mu * mu;
  const float rs = rsqrtf(var + 1e-5f);
  f32x4 g0 = *(const f32x4*)(gamma + tid * 8);
  f32x4 g1 = *(const f32x4*)(gamma + tid * 8 + 4);
  f32x4 b0 = *(const f32x4*)(beta + tid * 8);
  f32x4 b1 = *(const f32x4*)(beta + tid * 8 + 4);
  bf16x8 o;
#pragma unroll
  for (int j = 0; j < 4; ++j) {
    o[j] = (bf16)((v0[j] - mu) * rs * g0[j] + b0[j]);
    o[4 + j] = (bf16)((v1[j] - mu) * rs * g1[j] + b1[j]);
  }
  *(bf16x8*)(xn + base) = o;
}

// ---------------------------------------------------------------------------
// Inclusive cumsum of media_locations per batch -> window end index.
// ---------------------------------------------------------------------------
__global__ __launch_bounds__(256) void cumsum_end(const int* __restrict__ mloc,
                                                  int* __restrict__ endw) {
  const int b = blockIdx.x, tid = threadIdx.x;
  __shared__ int part[256];
  int loc[16];
  int s = 0;
  const int base = b * 4096 + tid * 16;
#pragma unroll
  for (int j = 0; j < 16; ++j) {
    loc[j] = (mloc[base + j] != 0) ? 1 : 0;
    s += loc[j];
  }
  part[tid] = s;
  __syncthreads();
  for (int off = 1; off < 256; off <<= 1) {
    int v = (tid >= off) ? part[tid - off] : 0;
    __syncthreads();
    part[tid] += v;
    __syncthreads();
  }
  int c = (tid > 0) ? part[tid - 1] : 0;
#pragma unroll
  for (int j = 0; j < 16; ++j) {
    c += loc[j];
    int e = (c > 1 ? c : 1) << 3;  // *W=8
    endw[base + j] = e > 64 ? 64 : e;
  }
}

// ---------------------------------------------------------------------------
// media_mask decode: detect 1-byte-bool vs int32 layout, normalize to int[256]
// ---------------------------------------------------------------------------
__global__ void decode_mask(const unsigned char* __restrict__ raw,
                            int* __restrict__ mk) {
  __shared__ int isbool;
  const int tid = threadIdx.x;
  if (tid == 0) isbool = 0;
  __syncthreads();
  const unsigned char v = raw[tid];
  if ((tid & 3) != 0 && v != 0) atomicOr(&isbool, 1);
  __syncthreads();
  mk[tid] = isbool ? (int)raw[tid] : ((const int*)raw)[tid];
}

// ---------------------------------------------------------------------------
// transpose + f32->bf16 (+scale):  dst[C][R] = src[R][C] * scale
// ---------------------------------------------------------------------------
__global__ __launch_bounds__(256) void transpose_to_bf16(
    const float* __restrict__ src, bf16* __restrict__ dst, int R, int C,
    float scale) {
  const int idx = blockIdx.x * 256 + threadIdx.x;
  if (idx >= R * C) return;
  const int c = idx / R, r = idx % R;
  dst[idx] = (bf16)(src[(size_t)r * C + c] * scale);
}

__global__ __launch_bounds__(256) void to_bf16_kernel(
    const float* __restrict__ s, bf16* __restrict__ d, int n) {
  const int i = blockIdx.x * 256 + threadIdx.x;
  if (i < n) d[i] = (bf16)s[i];
}

// vT[b][h][dh][l] = kv[b*64+l][512 + h*64 + dh]
__global__ __launch_bounds__(256) void build_vT(const bf16* __restrict__ kvb,
                                                bf16* __restrict__ vT) {
  const int idx = blockIdx.x * 256 + threadIdx.x;  // 131072
  const int l = idx & 63, rest = idx >> 6;
  const int dh = rest & 63, bh = rest >> 6;
  const int b = bh >> 3, h = bh & 7;
  vT[idx] = kvb[(size_t)(b * 64 + l) * 1024 + 512 + h * 64 + dh];
}

// ---------------------------------------------------------------------------
// Fused attention: block = (64 tokens, h, b); 4 waves, each owns 16 t-rows.
// QK^T (MFMA) -> mask -> softmax (shfl over 16-lane col groups) -> PV (MFMA).
// K, Vt, P tiles in LDS, 16B-slot XOR swizzle by (row&7) (128B rows).
// ---------------------------------------------------------------------------
__global__ __launch_bounds__(256, 2) void attn_kernel(
    const bf16* __restrict__ q, const bf16* __restrict__ kv,
    const bf16* __restrict__ vT, const int* __restrict__ mk,
    const int* __restrict__ endw, bf16* __restrict__ ao) {
  __shared__ bf16 Ks[64 * 64], Vs[64 * 64], Ps[64 * 64];
  __shared__ int mks[64];
  const int tid = threadIdx.x, lane = tid & 63, w = tid >> 6;
  const int b = blockIdx.z, h = blockIdx.y, t0 = blockIdx.x * 64;

#pragma unroll
  for (int s0 = 0; s0 < 2; ++s0) {
    const int sidx = s0 * 256 + tid;         // 512 slots of 16B
    const int r = sidx >> 3, sl = sidx & 7;  // row, 16B slot
    const int dsts = (sl ^ (r & 7)) << 3;
    *(bf16x8*)&Ks[r * 64 + dsts] =
        *(const bf16x8*)&kv[(size_t)(b * 64 + r) * 1024 + h * 64 + sl * 8];
    *(bf16x8*)&Vs[r * 64 + dsts] =
        *(const bf16x8*)&vT[((size_t)(b * 8 + h) * 64 + r) * 64 + sl * 8];
  }
  if (tid < 64) mks[tid] = mk[b * 64 + tid];
  __syncthreads();

  const int g = lane >> 4, fr = lane & 15;
  // Q fragments straight from global
  bf16x8 aq[2];
#pragma unroll
  for (int kg = 0; kg < 2; ++kg)
    aq[kg] = *(const bf16x8*)&q[(size_t)(b * 4096 + t0 + w * 16 + fr) * 512 +
                                h * 64 + kg * 32 + g * 8];
  f32x4 sacc[4] = {};
#pragma unroll
  for (int kg = 0; kg < 2; ++kg)
#pragma unroll
    for (int ni = 0; ni < 4; ++ni) {
      const int r = ni * 16 + fr;
      bf16x8 bk = *(const bf16x8*)&Ks[r * 64 + (((kg * 4 + g) ^ (r & 7)) << 3)];
      sacc[ni] = __builtin_amdgcn_mfma_f32_16x16x32_bf16(aq[kg], bk, sacc[ni],
                                                         0, 0, 0);
    }

  // mask + softmax (row t = t0 + w*16 + g*4 + rg; col l = ni*16 + fr)
  int ev[4];
#pragma unroll
  for (int rg = 0; rg < 4; ++rg)
    ev[rg] = endw[b * 4096 + t0 + w * 16 + g * 4 + rg];
  float p[4][4];
#pragma unroll
  for (int ni = 0; ni < 4; ++ni) {
    const int l = ni * 16 + fr;
    const bool mv = (mks[l] != 0);
#pragma unroll
    for (int rg = 0; rg < 4; ++rg)
      p[ni][rg] = (mv && (l < ev[rg])) ? sacc[ni][rg] : -FLT_MAX;
  }
#pragma unroll
  for (int rg = 0; rg < 4; ++rg) {
    float m = fmaxf(fmaxf(p[0][rg], p[1][rg]), fmaxf(p[2][rg], p[3][rg]));
    m = fmaxf(m, __shfl_xor(m, 1));
    m = fmaxf(m, __shfl_xor(m, 2));
    m = fmaxf(m, __shfl_xor(m, 4));
    m = fmaxf(m, __shfl_xor(m, 8));
    float sum = 0.f;
#pragma unroll
    for (int ni = 0; ni < 4; ++ni) {
      p[ni][rg] = __expf(p[ni][rg] - m);
      sum += p[ni][rg];
    }
    sum += __shfl_xor(sum, 1);
    sum += __shfl_xor(sum, 2);
    sum += __shfl_xor(sum, 4);
    sum += __shfl_xor(sum, 8);
    const float inv = 1.f / sum;
#pragma unroll
    for (int ni = 0; ni < 4; ++ni) p[ni][rg] *= inv;
  }
  // P -> LDS (bf16, swizzled)
#pragma unroll
  for (int ni = 0; ni < 4; ++ni) {
    const int l = ni * 16 + fr;
#pragma unroll
    for (int rg = 0; rg < 4; ++rg) {
      const int tr = w * 16 + g * 4 + rg;
      Ps[tr * 64 + ((((l >> 3) ^ (tr & 7)) << 3) | (l & 7))] = (bf16)p[ni][rg];
    }
  }
  __syncthreads();

  // PV
  bf16x8 pa[2];
#pragma unroll
  for (int kg = 0; kg < 2; ++kg) {
    const int r = w * 16 + fr;
    pa[kg] = *(const bf16x8*)&Ps[r * 64 + (((kg * 4 + g) ^ (r & 7)) << 3)];
  }
  f32x4 oacc[4] = {};
#pragma unroll
  for (int kg = 0; kg < 2; ++kg)
#pragma unroll
    for (int ni = 0; ni < 4; ++ni) {
      const int r = ni * 16 + fr;
      bf16x8 bv = *(const bf16x8*)&Vs[r * 64 + (((kg * 4 + g) ^ (r & 7)) << 3)];
      oacc[ni] = __builtin_amdgcn_mfma_f32_16x16x32_bf16(pa[kg], bv, oacc[ni],
                                                         0, 0, 0);
    }
#pragma unroll
  for (int ni = 0; ni < 4; ++ni)
#pragma unroll
    for (int rg = 0; rg < 4; ++rg)
      ao[(size_t)(b * 4096 + t0 + w * 16 + g * 4 + rg) * 512 + h * 64 +
         ni * 16 + fr] = (bf16)oacc[ni][rg];
}

// ---------------------------------------------------------------------------
extern "C" void kernel_launch(void* const* d_in, const int* in_sizes, int n_in,
                              void* d_out, int out_size, void* d_ws,
                              size_t ws_size, hipStream_t stream) {
  const float* x = (const float*)d_in[0];
  const float* media = (const float*)d_in[1];
  const unsigned char* mraw = (const unsigned char*)d_in[2];
  const int* mloc = (const int*)d_in[3];
  const float* Wq = (const float*)d_in[4];
  const float* Wkv = (const float*)d_in[5];
  const float* Wout = (const float*)d_in[6];
  const float* gamma = (const float*)d_in[7];
  const float* beta = (const float*)d_in[8];
  float* out = (float*)d_out;

  // xn (bf16, 67MB) lives in d_out scratch; dead before final GEMM overwrites.
  bf16* xn = (bf16*)d_out;

  char* ws = (char*)d_ws;
  size_t off = 0;
  auto carve = [&](size_t bytes) {
    void* p = ws + off;
    off += (bytes + 255) & ~(size_t)255;
    return p;
  };
  bf16* qb = (bf16*)carve((size_t)16384 * 512 * 2);
  bf16* aob = (bf16*)carve((size_t)16384 * 512 * 2);
  bf16* kvb = (bf16*)carve((size_t)256 * 1024 * 2);
  bf16* vTb = (bf16*)carve((size_t)4 * 8 * 64 * 64 * 2);
  bf16* wqT = (bf16*)carve((size_t)512 * 2048 * 2);
  bf16* wkvT = (bf16*)carve((size_t)1024 * 1024 * 2);
  bf16* woT = (bf16*)carve((size_t)2048 * 512 * 2);
  bf16* medb = (bf16*)carve((size_t)256 * 1024 * 2);
  int* endw = (int*)carve((size_t)4 * 4096 * 4);
  int* mk = (int*)carve(256 * 4);
  (void)ws_size;
  (void)in_sizes;
  (void)n_in;
  (void)out_size;

  // prep
  transpose_to_bf16<<<4096, 256, 0, stream>>>(Wq, wqT, 2048, 512, 0.125f);
  transpose_to_bf16<<<4096, 256, 0, stream>>>(Wkv, wkvT, 1024, 1024, 1.f);
  transpose_to_bf16<<<4096, 256, 0, stream>>>(Wout, woT, 512, 2048, 1.f);
  to_bf16_kernel<<<1024, 256, 0, stream>>>(media, medb, 262144);
  decode_mask<<<1, 256, 0, stream>>>(mraw, mk);
  cumsum_end<<<4, 256, 0, stream>>>(mloc, endw);
  ln_to_bf16<<<16384, 256, 0, stream>>>(x, gamma, beta, xn);

  // KV projection + V transpose
  gemm_bt<1><<<dim3(8, 2), 256, 0, stream>>>(medb, wkvT, kvb, 256, 1024, 1024);
  build_vT<<<512, 256, 0, stream>>>(kvb, vTb);

  // Q projection (scale folded into wqT)
  gemm_bt<1><<<dim3(4, 128), 256, 0, stream>>>(xn, wqT, qb, 16384, 512, 2048);

  // attention
  attn_kernel<<<dim3(64, 8, 4), 256, 0, stream>>>(qb, kvb, vTb, mk, endw, aob);

  // output projection (f32 out)
  gemm_bt<0><<<dim3(16, 128), 256, 0, stream>>>(aob, woT, out, 16384, 2048, 512);
}

// Round 2
// 186.089 us; speedup vs baseline: 1.1481x; 1.1481x over previous
//
#include <hip/hip_runtime.h>
#include <float.h>

typedef __bf16 bf16;
typedef __bf16 bf16x8 __attribute__((ext_vector_type(8)));
typedef float f32x4 __attribute__((ext_vector_type(4)));

#define GAS __attribute__((address_space(1)))
#define LAS __attribute__((address_space(3)))

__device__ __forceinline__ void gload_lds16(const void* g, void* l) {
  __builtin_amdgcn_global_load_lds((const GAS unsigned int*)g, (LAS unsigned int*)l, 16, 0, 0);
}

// ---------------------------------------------------------------------------
// GEMM: C[M,N] = A[M,K] @ Bt[N,K]^T, A/Bt bf16 row-major, 128x128 tile, BK=32.
// 4 waves (2x2), each wave 64x64 = 4x4 fragments of 16x16x32 MFMA.
// LDS 16B slots XOR-swizzled by (row&3); global source pre-swizzled for
// global_load_lds (linear dest = wave base + lane*16).
// XCD-chunked bijective blockIdx swizzle (m204): each XCD gets a contiguous
// chunk of linearized tiles -> A-panel reuse lands in that XCD's L2.
// ---------------------------------------------------------------------------
template <int OUT_BF16>
__global__ __launch_bounds__(256, 2) void gemm_bt(
    const bf16* __restrict__ A, const bf16* __restrict__ Bt,
    void* __restrict__ Cv, int M, int N, int K) {
  __shared__ bf16 As[128 * 32];
  __shared__ bf16 Bs[128 * 32];
  const int tid = threadIdx.x;
  const int lane = tid & 63, w = tid >> 6;
  const int wr = w >> 1, wc = w & 1;

  // bijective XCD-chunked swizzle
  const int gx = gridDim.x;
  const int nwg = gx * gridDim.y;
  int lid = blockIdx.y * gx + blockIdx.x;
  {
    const int qq = nwg >> 3, rr = nwg & 7;
    const int xcd = lid & 7, pos = lid >> 3;
    lid = (xcd < rr ? xcd * (qq + 1) : rr * (qq + 1) + (xcd - rr) * qq) + pos;
  }
  const int bx = lid % gx, by = lid / gx;
  const size_t m0 = (size_t)by * 128, n0 = (size_t)bx * 128;

  const int srow = lane >> 2, sslot = lane & 3;
  const int g = lane >> 4, fr = lane & 15;

  f32x4 acc[4][4] = {};

  for (int kt = 0; kt < K; kt += 32) {
    __syncthreads();  // previous-iter frag reads done before overwrite
#pragma unroll
    for (int j = 0; j < 2; ++j) {
      const int c = 2 * w + j;        // 1KB chunk id (16 rows of 64B)
      const int r = c * 16 + srow;    // tile row 0..127
      const int ks = (sslot ^ (r & 3)) << 3;  // pre-swizzled global k-slot
      gload_lds16(A + (m0 + r) * K + kt + ks, &As[c * 512]);
      gload_lds16(Bt + (n0 + r) * K + kt + ks, &Bs[c * 512]);
    }
    __syncthreads();  // compiler drains vmcnt(0) here
    bf16x8 av[4], bv[4];
#pragma unroll
    for (int mi = 0; mi < 4; ++mi) {
      const int r = wr * 64 + mi * 16 + fr;
      av[mi] = *(const bf16x8*)&As[r * 32 + ((g ^ (r & 3)) << 3)];
    }
#pragma unroll
    for (int ni = 0; ni < 4; ++ni) {
      const int r = wc * 64 + ni * 16 + fr;
      bv[ni] = *(const bf16x8*)&Bs[r * 32 + ((g ^ (r & 3)) << 3)];
    }
#pragma unroll
    for (int mi = 0; mi < 4; ++mi)
#pragma unroll
      for (int ni = 0; ni < 4; ++ni)
        acc[mi][ni] = __builtin_amdgcn_mfma_f32_16x16x32_bf16(
            av[mi], bv[ni], acc[mi][ni], 0, 0, 0);
  }

#pragma unroll
  for (int mi = 0; mi < 4; ++mi)
#pragma unroll
    for (int ni = 0; ni < 4; ++ni)
#pragma unroll
      for (int rg = 0; rg < 4; ++rg) {
        const size_t row = m0 + wr * 64 + mi * 16 + g * 4 + rg;
        const size_t col = n0 + wc * 64 + ni * 16 + fr;
        if (OUT_BF16)
          ((bf16*)Cv)[row * (size_t)N + col] = (bf16)acc[mi][ni][rg];
        else
          ((float*)Cv)[row * (size_t)N + col] = acc[mi][ni][rg];
      }
}

// ---------------------------------------------------------------------------
// Mega prep kernel: one launch, block-range partitioned.
//   [0,16384)       LayerNorm row -> bf16 xn
//   [16384,20480)   Wq transpose  (2048x512 -> 512x2048, *0.125)
//   [20480,24576)   Wkv transpose (1024x1024 -> 1024x1024)
//   [24576,28672)   Wout transpose (512x2048 -> 2048x512)
//   [28672,29696)   media f32 -> bf16 (262144)
//   [29696,29700)   cumsum window-end per batch
//   [29700]         media_mask decode (bool-byte vs int32) -> int[256]
// ---------------------------------------------------------------------------
__global__ __launch_bounds__(256) void prep_all(
    const float* __restrict__ x, const float* __restrict__ gamma,
    const float* __restrict__ beta, bf16* __restrict__ xn,
    const float* __restrict__ Wq, bf16* __restrict__ wqT,
    const float* __restrict__ Wkv, bf16* __restrict__ wkvT,
    const float* __restrict__ Wout, bf16* __restrict__ woT,
    const float* __restrict__ media, bf16* __restrict__ medb,
    const int* __restrict__ mloc, int* __restrict__ endw,
    const unsigned char* __restrict__ mraw, int* __restrict__ mk) {
  __shared__ float shf[256];
  const int blk = blockIdx.x, tid = threadIdx.x;

  if (blk < 16384) {
    // ---- LayerNorm (biased var) + cast to bf16 ----
    const size_t base = (size_t)blk * 2048 + tid * 8;
    f32x4 v0 = *(const f32x4*)(x + base);
    f32x4 v1 = *(const f32x4*)(x + base + 4);
    float s = 0.f, q2 = 0.f;
#pragma unroll
    for (int j = 0; j < 4; ++j) {
      s += v0[j] + v1[j];
      q2 += v0[j] * v0[j] + v1[j] * v1[j];
    }
    for (int off = 32; off > 0; off >>= 1) {
      s += __shfl_down(s, off);
      q2 += __shfl_down(q2, off);
    }
    const int lane = tid & 63, wv = tid >> 6;
    if (lane == 0) { shf[wv] = s; shf[4 + wv] = q2; }
    __syncthreads();
    s = shf[0] + shf[1] + shf[2] + shf[3];
    q2 = shf[4] + shf[5] + shf[6] + shf[7];
    const float mu = s * (1.f / 2048.f);
    const float var = q2 * (1.f / 2048.f) - mu * mu;
    const float rs = rsqrtf(var + 1e-5f);
    f32x4 g0 = *(const f32x4*)(gamma + tid * 8);
    f32x4 g1 = *(const f32x4*)(gamma + tid * 8 + 4);
    f32x4 b0 = *(const f32x4*)(beta + tid * 8);
    f32x4 b1 = *(const f32x4*)(beta + tid * 8 + 4);
    bf16x8 o;
#pragma unroll
    for (int j = 0; j < 4; ++j) {
      o[j] = (bf16)((v0[j] - mu) * rs * g0[j] + b0[j]);
      o[4 + j] = (bf16)((v1[j] - mu) * rs * g1[j] + b1[j]);
    }
    *(bf16x8*)(xn + base) = o;
  } else if (blk < 20480) {
    const int idx = (blk - 16384) * 256 + tid;   // dst[512][2048]
    const int c = idx >> 11, r = idx & 2047;     // src Wq[2048][512]
    wqT[idx] = (bf16)(Wq[(size_t)r * 512 + c] * 0.125f);
  } else if (blk < 24576) {
    const int idx = (blk - 20480) * 256 + tid;   // dst[1024][1024]
    const int c = idx >> 10, r = idx & 1023;     // src Wkv[1024][1024] wait: src rows = 1024 (DIM_A)
    wkvT[idx] = (bf16)Wkv[(size_t)r * 1024 + c];
  } else if (blk < 28672) {
    const int idx = (blk - 24576) * 256 + tid;   // dst[2048][512]
    const int c = idx >> 9, r = idx & 511;       // src Wout[512][2048]
    woT[idx] = (bf16)Wout[(size_t)r * 2048 + c];
  } else if (blk < 29696) {
    const int i = (blk - 28672) * 256 + tid;
    medb[i] = (bf16)media[i];
  } else if (blk < 29700) {
    // ---- cumsum -> window end ----
    int* part = (int*)shf;
    const int b = blk - 29696;
    int loc[16];
    int s = 0;
    const int base = b * 4096 + tid * 16;
#pragma unroll
    for (int j = 0; j < 16; ++j) {
      loc[j] = (mloc[base + j] != 0) ? 1 : 0;
      s += loc[j];
    }
    part[tid] = s;
    __syncthreads();
    for (int off = 1; off < 256; off <<= 1) {
      int v = (tid >= off) ? part[tid - off] : 0;
      __syncthreads();
      part[tid] += v;
      __syncthreads();
    }
    int c = (tid > 0) ? part[tid - 1] : 0;
#pragma unroll
    for (int j = 0; j < 16; ++j) {
      c += loc[j];
      int e = (c > 1 ? c : 1) << 3;  // *W=8
      endw[base + j] = e > 64 ? 64 : e;
    }
  } else {
    // ---- media_mask decode ----
    int* isbool = (int*)shf;
    if (tid == 0) *isbool = 0;
    __syncthreads();
    const unsigned char v = mraw[tid];
    if ((tid & 3) != 0 && v != 0) atomicOr(isbool, 1);
    __syncthreads();
    mk[tid] = (*isbool) ? (int)mraw[tid] : ((const int*)mraw)[tid];
  }
}

// ---------------------------------------------------------------------------
// Fused attention: block = (64 tokens, h, b); 4 waves, each owns 16 t-rows.
// Stages K rows and V TRANSPOSED (scatter write) from kvb; QK^T (MFMA) ->
// mask -> softmax (shfl over 16-lane col groups) -> PV (MFMA).
// K, Vt, P tiles in LDS, 16B-slot XOR swizzle by (row&7).
// ---------------------------------------------------------------------------
__global__ __launch_bounds__(256, 2) void attn_kernel(
    const bf16* __restrict__ q, const bf16* __restrict__ kv,
    const int* __restrict__ mk, const int* __restrict__ endw,
    bf16* __restrict__ ao) {
  __shared__ bf16 Ks[64 * 64], Vs[64 * 64], Ps[64 * 64];
  __shared__ int mks[64];
  const int tid = threadIdx.x, lane = tid & 63, w = tid >> 6;
  const int b = blockIdx.z, h = blockIdx.y, t0 = blockIdx.x * 64;

#pragma unroll
  for (int s0 = 0; s0 < 2; ++s0) {
    const int sidx = s0 * 256 + tid;         // 512 slots of 16B
    const int r = sidx >> 3, sl = sidx & 7;  // row (= l), 16B slot
    // K: row-major, swizzled slots
    *(bf16x8*)&Ks[r * 64 + ((sl ^ (r & 7)) << 3)] =
        *(const bf16x8*)&kv[(size_t)(b * 64 + r) * 1024 + h * 64 + sl * 8];
    // V: transpose on the fly. src: kv row l=r, 8 consecutive dh.
    // dst element (dh, l) at Vs[dh*64 + (((l>>3)^(dh&7))<<3 | (l&7))]
    bf16x8 vv =
        *(const bf16x8*)&kv[(size_t)(b * 64 + r) * 1024 + 512 + h * 64 + sl * 8];
#pragma unroll
    for (int j = 0; j < 8; ++j) {
      const int dh = sl * 8 + j;
      Vs[dh * 64 + ((((r >> 3) ^ (dh & 7)) << 3) | (r & 7))] = vv[j];
    }
  }
  if (tid < 64) mks[tid] = mk[b * 64 + tid];
  __syncthreads();

  const int g = lane >> 4, fr = lane & 15;
  // Q fragments straight from global
  bf16x8 aq[2];
#pragma unroll
  for (int kg = 0; kg < 2; ++kg)
    aq[kg] = *(const bf16x8*)&q[(size_t)(b * 4096 + t0 + w * 16 + fr) * 512 +
                                h * 64 + kg * 32 + g * 8];
  f32x4 sacc[4] = {};
#pragma unroll
  for (int kg = 0; kg < 2; ++kg)
#pragma unroll
    for (int ni = 0; ni < 4; ++ni) {
      const int r = ni * 16 + fr;
      bf16x8 bk = *(const bf16x8*)&Ks[r * 64 + (((kg * 4 + g) ^ (r & 7)) << 3)];
      sacc[ni] = __builtin_amdgcn_mfma_f32_16x16x32_bf16(aq[kg], bk, sacc[ni],
                                                         0, 0, 0);
    }

  // mask + softmax (row t = t0 + w*16 + g*4 + rg; col l = ni*16 + fr)
  const int4 ev4 = *(const int4*)&endw[b * 4096 + t0 + w * 16 + g * 4];
  const int ev[4] = {ev4.x, ev4.y, ev4.z, ev4.w};
  float p[4][4];
#pragma unroll
  for (int ni = 0; ni < 4; ++ni) {
    const int l = ni * 16 + fr;
    const bool mv = (mks[l] != 0);
#pragma unroll
    for (int rg = 0; rg < 4; ++rg)
      p[ni][rg] = (mv && (l < ev[rg])) ? sacc[ni][rg] : -FLT_MAX;
  }
#pragma unroll
  for (int rg = 0; rg < 4; ++rg) {
    float m = fmaxf(fmaxf(p[0][rg], p[1][rg]), fmaxf(p[2][rg], p[3][rg]));
    m = fmaxf(m, __shfl_xor(m, 1));
    m = fmaxf(m, __shfl_xor(m, 2));
    m = fmaxf(m, __shfl_xor(m, 4));
    m = fmaxf(m, __shfl_xor(m, 8));
    float sum = 0.f;
#pragma unroll
    for (int ni = 0; ni < 4; ++ni) {
      p[ni][rg] = __expf(p[ni][rg] - m);
      sum += p[ni][rg];
    }
    sum += __shfl_xor(sum, 1);
    sum += __shfl_xor(sum, 2);
    sum += __shfl_xor(sum, 4);
    sum += __shfl_xor(sum, 8);
    const float inv = 1.f / sum;
#pragma unroll
    for (int ni = 0; ni < 4; ++ni) p[ni][rg] *= inv;
  }
  // P -> LDS (bf16, swizzled)
#pragma unroll
  for (int ni = 0; ni < 4; ++ni) {
    const int l = ni * 16 + fr;
#pragma unroll
    for (int rg = 0; rg < 4; ++rg) {
      const int tr = w * 16 + g * 4 + rg;
      Ps[tr * 64 + ((((l >> 3) ^ (tr & 7)) << 3) | (l & 7))] = (bf16)p[ni][rg];
    }
  }
  __syncthreads();

  // PV
  bf16x8 pa[2];
#pragma unroll
  for (int kg = 0; kg < 2; ++kg) {
    const int r = w * 16 + fr;
    pa[kg] = *(const bf16x8*)&Ps[r * 64 + (((kg * 4 + g) ^ (r & 7)) << 3)];
  }
  f32x4 oacc[4] = {};
#pragma unroll
  for (int kg = 0; kg < 2; ++kg)
#pragma unroll
    for (int ni = 0; ni < 4; ++ni) {
      const int r = ni * 16 + fr;
      bf16x8 bv = *(const bf16x8*)&Vs[r * 64 + (((kg * 4 + g) ^ (r & 7)) << 3)];
      oacc[ni] = __builtin_amdgcn_mfma_f32_16x16x32_bf16(pa[kg], bv, oacc[ni],
                                                         0, 0, 0);
    }
#pragma unroll
  for (int ni = 0; ni < 4; ++ni)
#pragma unroll
    for (int rg = 0; rg < 4; ++rg)
      ao[(size_t)(b * 4096 + t0 + w * 16 + g * 4 + rg) * 512 + h * 64 +
         ni * 16 + fr] = (bf16)oacc[ni][rg];
}

// ---------------------------------------------------------------------------
extern "C" void kernel_launch(void* const* d_in, const int* in_sizes, int n_in,
                              void* d_out, int out_size, void* d_ws,
                              size_t ws_size, hipStream_t stream) {
  const float* x = (const float*)d_in[0];
  const float* media = (const float*)d_in[1];
  const unsigned char* mraw = (const unsigned char*)d_in[2];
  const int* mloc = (const int*)d_in[3];
  const float* Wq = (const float*)d_in[4];
  const float* Wkv = (const float*)d_in[5];
  const float* Wout = (const float*)d_in[6];
  const float* gamma = (const float*)d_in[7];
  const float* beta = (const float*)d_in[8];
  float* out = (float*)d_out;

  // xn (bf16, 67MB) lives in d_out scratch; dead before final GEMM overwrites.
  bf16* xn = (bf16*)d_out;

  char* ws = (char*)d_ws;
  size_t off = 0;
  auto carve = [&](size_t bytes) {
    void* p = ws + off;
    off += (bytes + 255) & ~(size_t)255;
    return p;
  };
  bf16* qb = (bf16*)carve((size_t)16384 * 512 * 2);
  bf16* aob = (bf16*)carve((size_t)16384 * 512 * 2);
  bf16* kvb = (bf16*)carve((size_t)256 * 1024 * 2);
  bf16* wqT = (bf16*)carve((size_t)512 * 2048 * 2);
  bf16* wkvT = (bf16*)carve((size_t)1024 * 1024 * 2);
  bf16* woT = (bf16*)carve((size_t)2048 * 512 * 2);
  bf16* medb = (bf16*)carve((size_t)256 * 1024 * 2);
  int* endw = (int*)carve((size_t)4 * 4096 * 4);
  int* mk = (int*)carve(256 * 4);
  (void)ws_size;
  (void)in_sizes;
  (void)n_in;
  (void)out_size;

  // one fused prep pass (LN, 3 weight transposes, media cast, cumsum, mask)
  prep_all<<<29701, 256, 0, stream>>>(x, gamma, beta, xn, Wq, wqT, Wkv, wkvT,
                                      Wout, woT, media, medb, mloc, endw, mraw,
                                      mk);

  // KV projection
  gemm_bt<1><<<dim3(8, 2), 256, 0, stream>>>(medb, wkvT, kvb, 256, 1024, 1024);

  // Q projection (scale folded into wqT)
  gemm_bt<1><<<dim3(4, 128), 256, 0, stream>>>(xn, wqT, qb, 16384, 512, 2048);

  // attention (V transposed on the fly from kvb)
  attn_kernel<<<dim3(64, 8, 4), 256, 0, stream>>>(qb, kvb, mk, endw, aob);

  // output projection (f32 out)
  gemm_bt<0><<<dim3(16, 128), 256, 0, stream>>>(aob, woT, out, 16384, 2048, 512);
}